// Round 5
// baseline (1595.074 us; speedup 1.0000x reference)
//
#include <hip/hip_runtime.h>
#include <hip/hip_bf16.h>
#include <cstdint>

// DeepDDT forward on MI355X.
//  - outs[7..14] dead in reference -> only attn GEMMs for nodes 7..14.
//  - comp = -pw * colmean(inp): colsum fused into calc epilogue, pw factored out.
//  - softmax+dist+sum fused into attn GEMM epilogue (S1=sum e, S2=sum dist*e).
//  - S1/S2: NO atomics; private slice per (block,wave): [15][16][8192].
//  - GEMM: 256x256 tile, 8 waves, 8-phase snake-quadrant schedule:
//    phases = C-quadrants (0,0)->(1,0)->(1,1)->(0,1); adjacent phases share
//    one operand set so only the CHANGED operand is re-read from LDS
//    (8/4 ds_read_b128 per phase vs 12-16 in failed r1/r2/r4 -> MFMA no longer
//    serialized behind LDS reads inside each phase).
//    Staging: 1 half-tile (2 global_load_lds) per phase, order [A0,B0,A1,B1],
//    one K-tile ahead; counted vmcnt(6) at p0/p1/p2 (3-phase distance), none
//    at p3; tail tile drains 4/2/0. Double-buffered 128 KiB LDS, chunk-XOR
//    swizzle (0 conflicts), setprio around MFMA clusters.
//  - per stage ONE dispatch: calc+attn merged via grid.z, padded grid.x.
//  - XCD-partitioned swizzle: id&7 owns a 4-row y-band of 256-row tiles.

#define NROWS 8192
#define HALFD 512

typedef __bf16 bf16x8 __attribute__((ext_vector_type(8)));
typedef short  short8 __attribute__((ext_vector_type(8)));
typedef float  f32x4  __attribute__((ext_vector_type(4)));

union FragU { short8 s; bf16x8 b; };

struct GArgs {
  const __hip_bfloat16* A0[4];
  const __hip_bfloat16* Bw[4];
  const float* bias[4];
  const float* pw[4];     // attn
  const float* cm0[4];    // attn: colsum of A0 half
  __hip_bfloat16* outB[4];// calc
  float* csOut[4];        // calc: colsum target (cs + firstOut*512)
  float* S1[4];           // attn: node-base S1 (16 slices per node)
  float* S2[4];
  int mode[4];            // 0 = calc, 1 = attn
  int gx[4];              // real x-tiles (256-wide) for this z
  int K[4];
};

__device__ __forceinline__ void gl2lds16(const void* g, void* l) {
  __builtin_amdgcn_global_load_lds((__attribute__((address_space(1))) void*)g,
                                   (__attribute__((address_space(3))) void*)l,
                                   16, 0, 0);
}

// ---------------- merged fp32 -> bf16 convert (5 regions, 1024 elems/block) ----------------
struct CvtArgs { const float* src[5]; __hip_bfloat16* dst[5]; int nblk[5]; };
__global__ void k_cvt(CvtArgs a) {
  int b = blockIdx.x, r = 0;
  while (b >= a.nblk[r]) { b -= a.nblk[r]; ++r; }
  const int i = (b * 256 + threadIdx.x) * 4;
  float4 v = *(const float4*)(a.src[r] + i);
  union { short4 s4; __hip_bfloat16 h[4]; } u;
  u.h[0] = __float2bfloat16(v.x);
  u.h[1] = __float2bfloat16(v.y);
  u.h[2] = __float2bfloat16(v.z);
  u.h[3] = __float2bfloat16(v.w);
  *(short4*)(a.dst[r] + i) = u.s4;
}

// ---------------- column sum of fp32 x [8192,512] ----------------
__global__ void k_colsum_f32(const float* __restrict__ src, float* __restrict__ dst) {
  int c  = blockIdx.x * 256 + threadIdx.x;   // grid (2,32)
  int r0 = blockIdx.y * 256;
  float s = 0.f;
  for (int r = 0; r < 256; ++r) s += src[(size_t)(r0 + r) * HALFD + c];
  atomicAdd(&dst[c], s);
}

// ---------------- 8-phase snake 256x256 bf16 MFMA GEMM ----------------
// LDS regions: As/Bs[buf][half][128 rows x 64 cols] bf16. Per phase, ALL 8
// waves compute ONE 128x128 C-quadrant: wave (wm,wn) owns rows wm*64+mi*16,
// cols wn*32+ni*16 within the quadrant (4x2 frags x 2 kk = 16 MFMA).
// Snake (mq,nq): p0(0,0) p1(1,0) p2(1,1) p3(0,1):
//   p0 reloads a(h0)+b(h0) [12 rd]; p1 a(h1) [8]; p2 b(h1) [4]; p3 a(h0) [8].
// Staging per phase (tile T+1): p0 A.h0, p1 B.h0, p2 A.h1, p3 B.h1.
// vmcnt ledger (2 insts/half-tile, in-order): outstanding before wait = 8
// insts at p1/p2 (10 at T=0.p0) -> vmcnt(6) retires exactly the half-tile
// needed this phase, staged 3 phases earlier. Tail (no staging): 4/2/0.

#define LDA(BUF, H) do { \
  _Pragma("unroll") for (int i_ = 0; i_ < 4; ++i_) \
  _Pragma("unroll") for (int k_ = 0; k_ < 2; ++k_) \
    a[i_][k_].s = *(const short8*)(&As[BUF][H][(wm * 64 + i_ * 16 + lr) * 64 + \
                                   (((k_ * 4 + lg) ^ sw) << 3)]); \
} while (0)

#define LDB(BUF, H) do { \
  _Pragma("unroll") for (int j_ = 0; j_ < 2; ++j_) \
  _Pragma("unroll") for (int k_ = 0; k_ < 2; ++k_) \
    b[j_][k_].s = *(const short8*)(&Bs[BUF][H][(wn * 32 + j_ * 16 + lr) * 64 + \
                                   (((k_ * 4 + lg) ^ sw) << 3)]); \
} while (0)

#define MFMA_Q(MQ, NQ) do { \
  _Pragma("unroll") for (int i_ = 0; i_ < 4; ++i_) \
  _Pragma("unroll") for (int j_ = 0; j_ < 2; ++j_) \
  _Pragma("unroll") for (int k_ = 0; k_ < 2; ++k_) \
    acc[MQ][NQ][i_][j_] = __builtin_amdgcn_mfma_f32_16x16x32_bf16( \
        a[i_][k_].b, b[j_][k_].b, acc[MQ][NQ][i_][j_], 0, 0, 0); \
} while (0)

#define STG_A(NB, H) do { \
  gl2lds16(aS + (size_t)((H) * 128) * HALFD,      (char*)&As[NB][H][0] + wvB); \
  gl2lds16(aS + (size_t)((H) * 128 + 64) * HALFD, (char*)&As[NB][H][0] + 8192 + wvB); \
} while (0)

#define STG_B(NB, H) do { \
  gl2lds16(bS + (size_t)((H) * 128) * K,      (char*)&Bs[NB][H][0] + wvB); \
  gl2lds16(bS + (size_t)((H) * 128 + 64) * K, (char*)&Bs[NB][H][0] + 8192 + wvB); \
} while (0)

#define TILE_BODY(BUF, NB, STG) do { \
  /* p0: Q(0,0) */ \
  if (STG) { STG_A(NB, 0); asm volatile("s_waitcnt vmcnt(6)" ::: "memory"); } \
  else     { asm volatile("s_waitcnt vmcnt(4)" ::: "memory"); } \
  __builtin_amdgcn_s_barrier(); \
  LDA(BUF, 0); LDB(BUF, 0); \
  __builtin_amdgcn_s_setprio(1); MFMA_Q(0, 0); __builtin_amdgcn_s_setprio(0); \
  __builtin_amdgcn_s_barrier(); \
  /* p1: Q(1,0) — b(h0) reused */ \
  if (STG) { STG_B(NB, 0); asm volatile("s_waitcnt vmcnt(6)" ::: "memory"); } \
  else     { asm volatile("s_waitcnt vmcnt(2)" ::: "memory"); } \
  __builtin_amdgcn_s_barrier(); \
  LDA(BUF, 1); \
  __builtin_amdgcn_s_setprio(1); MFMA_Q(1, 0); __builtin_amdgcn_s_setprio(0); \
  __builtin_amdgcn_s_barrier(); \
  /* p2: Q(1,1) — a(h1) reused */ \
  if (STG) { STG_A(NB, 1); asm volatile("s_waitcnt vmcnt(6)" ::: "memory"); } \
  else     { asm volatile("s_waitcnt vmcnt(0)" ::: "memory"); } \
  __builtin_amdgcn_s_barrier(); \
  LDB(BUF, 1); \
  __builtin_amdgcn_s_setprio(1); MFMA_Q(1, 1); __builtin_amdgcn_s_setprio(0); \
  __builtin_amdgcn_s_barrier(); \
  /* p3: Q(0,1) — b(h1) reused, a(h0) reloaded; no wait needed */ \
  if (STG) { STG_B(NB, 1); } \
  __builtin_amdgcn_s_barrier(); \
  LDA(BUF, 0); \
  __builtin_amdgcn_s_setprio(1); MFMA_Q(0, 1); __builtin_amdgcn_s_setprio(0); \
  __builtin_amdgcn_s_barrier(); \
} while (0)

__global__ __launch_bounds__(512, 2)
void k_gemm(GArgs ga, const __hip_bfloat16* __restrict__ A1,
            const float* __restrict__ cm1) {
  __shared__ alignas(16) short As[2][2][128 * 64];
  __shared__ alignas(16) short Bs[2][2][128 * 64];

  const int z = blockIdx.z;
  // XCD-partitioned swizzle: xcd = id&7 owns y in [xcd*4, xcd*4+4), x slow.
  const int id  = blockIdx.x + gridDim.x * blockIdx.y;
  const int xcd = id & 7;
  const int q   = id >> 3;
  const int bx  = q >> 2;
  const int by  = xcd * 4 + (q & 3);
  if (bx >= ga.gx[z]) return;

  const __hip_bfloat16* __restrict__ Ah0 = ga.A0[z];
  const __hip_bfloat16* __restrict__ Bw  = ga.Bw[z];
  const float* __restrict__ bias = ga.bias[z];
  const int K  = ga.K[z];
  const int NT = K >> 6;

  const int tid  = threadIdx.x;
  const int lane = tid & 63;
  const int wv   = tid >> 6;           // 0..7
  const int wm   = wv >> 2, wn = wv & 3;   // role within each 128x128 quadrant
  const int lr   = lane & 15, lg = lane >> 4;
  const int sw   = lr & 7;
  const int wvB  = wv * 1024;
  const int row0 = by * 256;
  const int col0 = bx * 256;

  f32x4 acc[2][2][4][2];
#pragma unroll
  for (int mq = 0; mq < 2; ++mq)
#pragma unroll
    for (int nq = 0; nq < 2; ++nq)
#pragma unroll
      for (int i = 0; i < 4; ++i)
#pragma unroll
        for (int j = 0; j < 2; ++j)
#pragma unroll
          for (int e = 0; e < 4; ++e) acc[mq][nq][i][j][e] = 0.f;

  FragU a[4][2], b[2][2];

  // staging thread mapping: thread tid covers row (tid>>3), chunk (tid&7),
  // pre-swizzled source chunk gc = (tid&7) ^ ((tid>>3)&7).
  const int gc = (tid & 7) ^ ((tid >> 3) & 7);
  const size_t aoff = (size_t)(row0 + (tid >> 3)) * HALFD + gc * 8;
  const size_t boff = (size_t)(col0 + (tid >> 3)) * (size_t)K + gc * 8;

  const __hip_bfloat16* aS = Ah0 + aoff;
  const __hip_bfloat16* bS = Bw + boff;

  // prologue: stage tile 0 into buf0, order [A0,B0,A1,B1] (matches ledger)
  STG_A(0, 0); STG_B(0, 0); STG_A(0, 1); STG_B(0, 1);

  for (int T = 0; T < NT; ++T) {
    const int sn  = T + 1;
    const int stg = sn < NT;
    if (stg) {
      aS = ((sn < 8) ? Ah0 : A1) + ((sn & 7) << 6) + aoff;
      bS = Bw + (size_t)sn * 64 + boff;
    }
    if (T & 1) TILE_BODY(1, 0, stg);
    else       TILE_BODY(0, 1, stg);
  }

  if (ga.mode[z] == 0) {
    // CALC: relu+bias -> bf16 outs, fused column-sum
    __hip_bfloat16* outB = ga.outB[z];
    float* csOut = ga.csOut[z];
#pragma unroll
    for (int nq = 0; nq < 2; ++nq) {
#pragma unroll
      for (int ni = 0; ni < 2; ++ni) {
        const int col  = col0 + nq * 128 + wn * 32 + ni * 16 + lr;
        const float bv = bias[col];
        __hip_bfloat16* op = outB + (size_t)(col >> 9) * ((size_t)NROWS * HALFD) + (col & 511);
        float csum = 0.f;
#pragma unroll
        for (int mq = 0; mq < 2; ++mq) {
#pragma unroll
          for (int mi = 0; mi < 4; ++mi) {
#pragma unroll
            for (int rg = 0; rg < 4; ++rg) {
              const int row = row0 + mq * 128 + wm * 64 + mi * 16 + lg * 4 + rg;
              float v = acc[mq][nq][mi][ni][rg] + bv;
              v = v > 0.f ? v : 0.f;
              csum += v;
              op[(size_t)row * HALFD] = __float2bfloat16(v);
            }
          }
        }
        csum += __shfl_xor(csum, 16);
        csum += __shfl_xor(csum, 32);
        if (lg == 0) atomicAdd(&csOut[col], csum);
      }
    }
  } else {
    // ATTN: S1 = sum_n e^{C+ab}; S2 = sum_n sigmoid(pw*(inp-cm))*e^{C+ab}
    // private slice (no atomics): slice = (bx&3)*4 + wn.
    const float* __restrict__ pw  = ga.pw[z];
    const float* __restrict__ cm0 = ga.cm0[z];
    const int node  = col0 >> 10;
    const int slice = ((bx & 3) << 2) | wn;
    float* s1p = ga.S1[z] + (size_t)(node * 16 + slice) * NROWS;
    float* s2p = ga.S2[z] + (size_t)(node * 16 + slice) * NROWS;
    float bv[2][2], pwv[2][2], cmv[2][2];
    const __hip_bfloat16* Ain[2][2];
#pragma unroll
    for (int nq = 0; nq < 2; ++nq) {
#pragma unroll
      for (int ni = 0; ni < 2; ++ni) {
        const int col = col0 + nq * 128 + wn * 32 + ni * 16 + lr;
        bv[nq][ni]  = bias[col];
        pwv[nq][ni] = pw[col];
        const int ii   = col & 1023;
        const int half = ii >> 9;
        const int cc   = ii & 511;
        cmv[nq][ni] = (half ? cm1[cc] : cm0[cc]) * (1.f / 8192.f);
        Ain[nq][ni] = (half ? A1 : Ah0) + cc;
      }
    }
#pragma unroll
    for (int mq = 0; mq < 2; ++mq) {
#pragma unroll
      for (int mi = 0; mi < 4; ++mi) {
#pragma unroll
        for (int rg = 0; rg < 4; ++rg) {
          const int row = row0 + mq * 128 + wm * 64 + mi * 16 + lg * 4 + rg;
          float s1 = 0.f, s2 = 0.f;
#pragma unroll
          for (int nq = 0; nq < 2; ++nq) {
#pragma unroll
            for (int ni = 0; ni < 2; ++ni) {
              const float l = acc[mq][nq][mi][ni][rg] + bv[nq][ni];
              const float e = __expf(l);
              const float inpv = __bfloat162float(Ain[nq][ni][(size_t)row * HALFD]);
              const float zz = pwv[nq][ni] * (inpv - cmv[nq][ni]);
              const float dist = 1.f / (1.f + __expf(-zz));
              s1 += e;
              s2 += dist * e;
            }
          }
#pragma unroll
          for (int off = 1; off < 16; off <<= 1) {
            s1 += __shfl_xor(s1, off);
            s2 += __shfl_xor(s2, off);
          }
          if (lr == 0) {
            s1p[row] = s1;
            s2p[row] = s2;
          }
        }
      }
    }
  }
}

// ---------------- finalize: slice-reduce, tree product, leaf matmul, softmax ----------------
__global__ void k_finalize(const float* __restrict__ S1, const float* __restrict__ S2,
                           const float* __restrict__ leaf_out, float* __restrict__ out) {
  const int r    = (blockIdx.x * 256 + threadIdx.x) >> 6;  // one wave per row
  const int lane = threadIdx.x & 63;
  float pb[31];
  pb[0] = 1.f;
#pragma unroll
  for (int n = 0; n < 15; ++n) {
    float a1 = 0.f, a2 = 0.f;
#pragma unroll
    for (int s = 0; s < 16; ++s) {
      a1 += S1[((size_t)n * 16 + s) * NROWS + r];
      a2 += S2[((size_t)n * 16 + s) * NROWS + r];
    }
    const float p = a2 / a1;
    pb[2 * n + 1] = pb[n] * (1.f - p);
    pb[2 * n + 2] = pb[n] * p;
  }
  float a = 0.f;
#pragma unroll
  for (int i = 0; i < 16; ++i) a += pb[15 + i] * leaf_out[i * 64 + lane];
  float m = a;
#pragma unroll
  for (int off = 1; off < 64; off <<= 1) m = fmaxf(m, __shfl_xor(m, off));
  const float e = __expf(a - m);
  float s = e;
#pragma unroll
  for (int off = 1; off < 64; off <<= 1) s += __shfl_xor(s, off);
  out[(size_t)r * 64 + lane] = e / s;
}

// ---------------- workspace layout (bytes) ----------------
static constexpr size_t O_S1   = 0;                               // 15*16*8192 f32
static constexpr size_t O_S2   = O_S1 + (size_t)15 * 16 * NROWS * 4;
static constexpr size_t O_XSUM = O_S2 + (size_t)15 * 16 * NROWS * 4;
static constexpr size_t O_CS   = O_XSUM + 512 * 4;                // 7 x 512 f32
static constexpr size_t O_ZEND = O_CS + 7 * 512 * 4;              // memset range
static constexpr size_t O_XB   = O_ZEND;                          // bf16 x [8192,512]
static constexpr size_t O_OUTS = O_XB + (size_t)NROWS * HALFD * 2;
static constexpr size_t O_CW0  = O_OUTS + 7 * (size_t)NROWS * HALFD * 2;
static constexpr size_t O_AW0  = O_CW0 + (size_t)512 * 512 * 2;
static constexpr size_t O_CW   = O_AW0 + (size_t)512 * 512 * 2;
static constexpr size_t O_AW   = O_CW + (size_t)14 * 512 * 1024 * 2;

extern "C" void kernel_launch(void* const* d_in, const int* in_sizes, int n_in,
                              void* d_out, int out_size, void* d_ws, size_t ws_size,
                              hipStream_t stream) {
  const float* x        = (const float*)d_in[0];
  const float* calc_b0  = (const float*)d_in[2];
  const float* prob_w0  = (const float*)d_in[3];
  const float* attn_b0  = (const float*)d_in[5];
  const float* calc_b   = (const float*)d_in[7];
  const float* prob_w   = (const float*)d_in[8];
  const float* attn_b   = (const float*)d_in[10];
  const float* leaf_out = (const float*)d_in[11];
  float* out = (float*)d_out;
  char* ws = (char*)d_ws;

  float* S1   = (float*)(ws + O_S1);
  float* S2   = (float*)(ws + O_S2);
  float* xsum = (float*)(ws + O_XSUM);
  float* cs   = (float*)(ws + O_CS);  // cs + n*512 = colsum of outs[n]
  __hip_bfloat16* xb   = (__hip_bfloat16*)(ws + O_XB);
  __hip_bfloat16* outs = (__hip_bfloat16*)(ws + O_OUTS);
  __hip_bfloat16* cW0b = (__hip_bfloat16*)(ws + O_CW0);
  __hip_bfloat16* aW0b = (__hip_bfloat16*)(ws + O_AW0);
  __hip_bfloat16* cWb  = (__hip_bfloat16*)(ws + O_CW);
  __hip_bfloat16* aWb  = (__hip_bfloat16*)(ws + O_AW);
  const size_t OSZ = (size_t)NROWS * HALFD;  // elements per outs buffer
  const size_t NSL = (size_t)16 * NROWS;     // slice-block per node

  hipMemsetAsync(d_ws, 0, O_ZEND, stream);

  // merged converts (elements all divisible by 1024)
  {
    CvtArgs ca{};
    ca.src[0] = x;                     ca.dst[0] = xb;   ca.nblk[0] = NROWS * HALFD / 1024;
    ca.src[1] = (const float*)d_in[1]; ca.dst[1] = cW0b; ca.nblk[1] = 512 * 512 / 1024;
    ca.src[2] = (const float*)d_in[4]; ca.dst[2] = aW0b; ca.nblk[2] = 512 * 512 / 1024;
    ca.src[3] = (const float*)d_in[6]; ca.dst[3] = cWb;  ca.nblk[3] = 14 * 512 * 1024 / 1024;
    ca.src[4] = (const float*)d_in[9]; ca.dst[4] = aWb;  ca.nblk[4] = 14 * 1024 * 1024 / 1024;
    int tot = ca.nblk[0] + ca.nblk[1] + ca.nblk[2] + ca.nblk[3] + ca.nblk[4];
    k_cvt<<<tot, 256, 0, stream>>>(ca);
  }
  k_colsum_f32<<<dim3(2, 32), 256, 0, stream>>>(x, xsum);

  // ---- stage 0: root calc + root attn (K=512, N=512) ----
  {
    GArgs ga{};
    ga.mode[0] = 0; ga.gx[0] = 2; ga.K[0] = 512;
    ga.A0[0] = xb; ga.Bw[0] = cW0b; ga.bias[0] = calc_b0;
    ga.outB[0] = outs; ga.csOut[0] = cs;
    ga.mode[1] = 1; ga.gx[1] = 2; ga.K[1] = 512;
    ga.A0[1] = xb; ga.Bw[1] = aW0b; ga.bias[1] = attn_b0;
    ga.pw[1] = prob_w0; ga.cm0[1] = xsum;
    ga.S1[1] = S1; ga.S2[1] = S2;
    k_gemm<<<dim3(2, 32, 2), 512, 0, stream>>>(ga, xb, xsum);
  }
  // ---- stage 1: calc nodes 1,2 + attn nodes 1,2 (A=[outs0|x]) ----
  {
    GArgs ga{};
    ga.mode[0] = 0; ga.gx[0] = 4; ga.K[0] = 1024;
    ga.A0[0] = outs; ga.Bw[0] = cWb; ga.bias[0] = calc_b;
    ga.outB[0] = outs + OSZ; ga.csOut[0] = cs + 512;
    ga.mode[1] = 1; ga.gx[1] = 8; ga.K[1] = 1024;
    ga.A0[1] = outs; ga.Bw[1] = aWb; ga.bias[1] = attn_b;
    ga.pw[1] = prob_w; ga.cm0[1] = cs;
    ga.S1[1] = S1 + (size_t)1 * NSL; ga.S2[1] = S2 + (size_t)1 * NSL;
    k_gemm<<<dim3(8, 32, 2), 512, 0, stream>>>(ga, xb, xsum);
  }
  // ---- stage 2: calc nodes 3,4 (outs1) & 5,6 (outs2) + attn nodes 3..6 ----
  {
    GArgs ga{};
    for (int i = 0; i < 2; ++i) {
      ga.mode[i] = 0; ga.gx[i] = 4; ga.K[i] = 1024;
      ga.A0[i] = outs + (size_t)(1 + i) * OSZ;
      ga.Bw[i] = cWb + (size_t)(2 + 2 * i) * 512 * 1024;
      ga.bias[i] = calc_b + (2 + 2 * i) * 512;
      ga.outB[i] = outs + (size_t)(3 + 2 * i) * OSZ;
      ga.csOut[i] = cs + (size_t)(3 + 2 * i) * 512;
    }
    for (int i = 0; i < 2; ++i) {
      const int zi = 2 + i;
      ga.mode[zi] = 1; ga.gx[zi] = 8; ga.K[zi] = 1024;
      ga.A0[zi] = outs + (size_t)(1 + i) * OSZ;
      ga.Bw[zi] = aWb + (size_t)(2 + 2 * i) * 1024 * 1024;
      ga.bias[zi] = attn_b + (2 + 2 * i) * 1024;
      ga.pw[zi] = prob_w + (2 + 2 * i) * 1024;
      ga.cm0[zi] = cs + (size_t)(1 + i) * 512;
      ga.S1[zi] = S1 + (size_t)(3 + 2 * i) * NSL;
      ga.S2[zi] = S2 + (size_t)(3 + 2 * i) * NSL;
    }
    k_gemm<<<dim3(8, 32, 4), 512, 0, stream>>>(ga, xb, xsum);
  }
  // ---- stage 3: attn nodes 7..14 (outs[7..14] dead) ----
  {
    GArgs ga{};
    for (int i = 0; i < 4; ++i) {
      ga.mode[i] = 1; ga.gx[i] = 8; ga.K[i] = 1024;
      ga.A0[i] = outs + (size_t)(3 + i) * OSZ;
      ga.Bw[i] = aWb + (size_t)(6 + 2 * i) * 1024 * 1024;
      ga.bias[i] = attn_b + (6 + 2 * i) * 1024;
      ga.pw[i] = prob_w + (6 + 2 * i) * 1024;
      ga.cm0[i] = cs + (size_t)(3 + i) * 512;
      ga.S1[i] = S1 + (size_t)(7 + 2 * i) * NSL;
      ga.S2[i] = S2 + (size_t)(7 + 2 * i) * NSL;
    }
    k_gemm<<<dim3(8, 32, 4), 512, 0, stream>>>(ga, xb, xsum);
  }

  // ---- finalize ----
  k_finalize<<<NROWS * 64 / 256, 256, 0, stream>>>(S1, S2, leaf_out, out);
}

// Round 6
// 593.847 us; speedup vs baseline: 2.6860x; 2.6860x over previous
//
#include <hip/hip_runtime.h>
#include <hip/hip_bf16.h>
#include <cstdint>

// DeepDDT forward on MI355X.
//  - outs[7..14] dead in reference -> only attn GEMMs for nodes 7..14.
//  - comp = -pw * colmean(inp): colsum fused into calc epilogue, pw factored out.
//  - softmax+dist+sum fused into attn GEMM epilogue (S1=sum e, S2=sum dist*e).
//  - S1/S2: NO atomics; private slice per (block,wave): [15][16][8192].
//    Only node 0's slice block needs zero-init (gx=4 -> slices 8..15 unwritten);
//    nodes 1..14 fully written -> memset trimmed 15.7MB -> 1MB.
//  - GEMM: r3-proven 128x128 tile, BK=64, 2-barrier loop, chunk-XOR swizzled
//    LDS (0 bank conflicts), global_load_lds dwordx4 staging. 256²/8-phase
//    ports tried r1/r2/r4/r5: all regressed (wait-distance, phase overhead,
//    reg spills at 9% MfmaUtil/1.7GB scratch writes) -> line closed; this
//    structure measures at its ceiling for K=1024 (739 TF vs ~790 expected).
//  - per stage ONE dispatch: calc+attn merged via grid.z, padded grid.x.
//  - XCD-partitioned swizzle: id&7 owns an 8-row y-band (B-tile reused 8x
//    consecutively; per-XCD working set ~2.25MB < 4MB L2/XCD).

#define NROWS 8192
#define HALFD 512

typedef __bf16 bf16x8 __attribute__((ext_vector_type(8)));
typedef short  short8 __attribute__((ext_vector_type(8)));
typedef float  f32x4  __attribute__((ext_vector_type(4)));

union FragU { short8 s; bf16x8 b; };

struct GArgs {
  const __hip_bfloat16* A0[4];
  const __hip_bfloat16* Bw[4];
  const float* bias[4];
  const float* pw[4];     // attn
  const float* cm0[4];    // attn: colsum of A0 half
  __hip_bfloat16* outB[4];// calc
  float* csOut[4];        // calc: colsum target (cs + firstOut*512)
  float* S1[4];           // attn: node-base S1 (16 slices per node)
  float* S2[4];
  int mode[4];            // 0 = calc, 1 = attn
  int gx[4];              // real x-tiles for this z
  int K[4];
};

__device__ __forceinline__ void gl2lds16(const void* g, void* l) {
  __builtin_amdgcn_global_load_lds((__attribute__((address_space(1))) void*)g,
                                   (__attribute__((address_space(3))) void*)l,
                                   16, 0, 0);
}

// ---------------- merged fp32 -> bf16 convert (5 regions, 1024 elems/block) ----------------
struct CvtArgs { const float* src[5]; __hip_bfloat16* dst[5]; int nblk[5]; };
__global__ void k_cvt(CvtArgs a) {
  int b = blockIdx.x, r = 0;
  while (b >= a.nblk[r]) { b -= a.nblk[r]; ++r; }
  const int i = (b * 256 + threadIdx.x) * 4;
  float4 v = *(const float4*)(a.src[r] + i);
  union { short4 s4; __hip_bfloat16 h[4]; } u;
  u.h[0] = __float2bfloat16(v.x);
  u.h[1] = __float2bfloat16(v.y);
  u.h[2] = __float2bfloat16(v.z);
  u.h[3] = __float2bfloat16(v.w);
  *(short4*)(a.dst[r] + i) = u.s4;
}

// ---------------- column sum of fp32 x [8192,512] ----------------
__global__ void k_colsum_f32(const float* __restrict__ src, float* __restrict__ dst) {
  int c  = blockIdx.x * 256 + threadIdx.x;   // grid (2,32)
  int r0 = blockIdx.y * 256;
  float s = 0.f;
  for (int r = 0; r < 256; ++r) s += src[(size_t)(r0 + r) * HALFD + c];
  atomicAdd(&dst[c], s);
}

// ---------------- bf16 MFMA GEMM, 128x128 tile, BK=64, swizzled LDS ----------------
__global__ __launch_bounds__(256, 2)
void k_gemm(GArgs ga, const __hip_bfloat16* __restrict__ A1,
            const float* __restrict__ cm1) {
  __shared__ alignas(16) short As[128 * 64];
  __shared__ alignas(16) short Bs[128 * 64];

  const int z = blockIdx.z;
  // XCD-partitioned swizzle: xcd = id&7 owns y in [xcd*8, xcd*8+8), x slow.
  const int id  = blockIdx.x + gridDim.x * blockIdx.y;
  const int xcd = id & 7;
  const int q   = id >> 3;
  const int bx  = q >> 3;
  const int by  = xcd * 8 + (q & 7);
  if (bx >= ga.gx[z]) return;

  const __hip_bfloat16* __restrict__ Ah0 = ga.A0[z];
  const __hip_bfloat16* __restrict__ Bw  = ga.Bw[z];
  const float* __restrict__ bias = ga.bias[z];
  const int K = ga.K[z];

  const int tid  = threadIdx.x;
  const int lane = tid & 63;
  const int wv   = tid >> 6;
  const int wm   = wv >> 1, wn = wv & 1;
  const int lr   = lane & 15, lg = lane >> 4;
  const int row0 = by * 128;
  const int col0 = bx * 128;

  f32x4 acc[4][4];
#pragma unroll
  for (int i = 0; i < 4; ++i)
#pragma unroll
    for (int j = 0; j < 4; ++j)
#pragma unroll
      for (int e = 0; e < 4; ++e) acc[i][j][e] = 0.f;

  const int sr = tid >> 3;                          // staging row (0..31/round)
  const int sc = (((tid & 7) ^ (sr & 7)) << 3);     // XOR-swizzled source chunk
  const int sw = lr & 7;                            // reader's swizzle key

  for (int kt = 0; kt < K; kt += 64) {
    const __hip_bfloat16* Asrc = (kt < HALFD) ? Ah0 : A1;
    const int kl = kt & (HALFD - 1);
    __syncthreads();
#pragma unroll
    for (int rnd = 0; rnd < 4; ++rnd) {
      const int r = rnd * 32 + sr;
      gl2lds16(Asrc + (size_t)(row0 + r) * HALFD + kl + sc,
               (char*)As + rnd * 4096 + wv * 1024);
      gl2lds16(Bw + (size_t)(col0 + r) * K + kt + sc,
               (char*)Bs + rnd * 4096 + wv * 1024);
    }
    __syncthreads();
#pragma unroll
    for (int kk = 0; kk < 64; kk += 32) {
      FragU a[4], b[4];
#pragma unroll
      for (int mi = 0; mi < 4; ++mi)
        a[mi].s = *(const short8*)(As + (wm * 64 + mi * 16 + lr) * 64 +
                                   ((((kk >> 3) + lg) ^ sw) << 3));
#pragma unroll
      for (int ni = 0; ni < 4; ++ni)
        b[ni].s = *(const short8*)(Bs + (wn * 64 + ni * 16 + lr) * 64 +
                                   ((((kk >> 3) + lg) ^ sw) << 3));
#pragma unroll
      for (int mi = 0; mi < 4; ++mi)
#pragma unroll
        for (int ni = 0; ni < 4; ++ni)
          acc[mi][ni] = __builtin_amdgcn_mfma_f32_16x16x32_bf16(a[mi].b, b[ni].b,
                                                               acc[mi][ni], 0, 0, 0);
    }
  }

  if (ga.mode[z] == 0) {
    // CALC: relu+bias -> bf16 outs, fused column-sum (shuffle over lg, 1 atomic/col/wave)
    __hip_bfloat16* outB = ga.outB[z];
    float* csOut = ga.csOut[z];
#pragma unroll
    for (int ni = 0; ni < 4; ++ni) {
      const int col  = col0 + wn * 64 + ni * 16 + lr;
      const float bv = bias[col];
      __hip_bfloat16* op = outB + (size_t)(col >> 9) * ((size_t)NROWS * HALFD) + (col & 511);
      float csum = 0.f;
#pragma unroll
      for (int mi = 0; mi < 4; ++mi) {
#pragma unroll
        for (int rg = 0; rg < 4; ++rg) {
          const int row = row0 + wm * 64 + mi * 16 + lg * 4 + rg;
          float v = acc[mi][ni][rg] + bv;
          v = v > 0.f ? v : 0.f;
          csum += v;
          op[(size_t)row * HALFD] = __float2bfloat16(v);
        }
      }
      csum += __shfl_xor(csum, 16);
      csum += __shfl_xor(csum, 32);
      if (lg == 0) atomicAdd(&csOut[col], csum);
    }
  } else {
    // ATTN: S1 = sum_n e^{C+ab}; S2 = sum_n sigmoid(pw*(inp-cm))*e^{C+ab}
    // written to private slice (no atomics): slice = (bx&7)*2 + wn.
    const float* __restrict__ pw  = ga.pw[z];
    const float* __restrict__ cm0 = ga.cm0[z];
    const int node  = col0 >> 10;                 // which node within this z
    const int slice = ((bx & 7) << 1) | wn;
    float* s1p = ga.S1[z] + (size_t)(node * 16 + slice) * NROWS;
    float* s2p = ga.S2[z] + (size_t)(node * 16 + slice) * NROWS;
    float bv[4], pwv[4], cmv[4];
    const __hip_bfloat16* Ain[4];
#pragma unroll
    for (int ni = 0; ni < 4; ++ni) {
      const int col = col0 + wn * 64 + ni * 16 + lr;
      bv[ni]  = bias[col];
      pwv[ni] = pw[col];
      const int ii   = col & 1023;
      const int half = ii >> 9;
      const int cc   = ii & 511;
      cmv[ni] = (half ? cm1[cc] : cm0[cc]) * (1.f / 8192.f);
      Ain[ni] = (half ? A1 : Ah0) + cc;
    }
#pragma unroll
    for (int mi = 0; mi < 4; ++mi) {
#pragma unroll
      for (int rg = 0; rg < 4; ++rg) {
        const int row = row0 + wm * 64 + mi * 16 + lg * 4 + rg;
        float s1 = 0.f, s2 = 0.f;
#pragma unroll
        for (int ni = 0; ni < 4; ++ni) {
          const float l = acc[mi][ni][rg] + bv[ni];
          const float e = __expf(l);
          const float inpv = __bfloat162float(Ain[ni][(size_t)row * HALFD]);
          const float zz = pwv[ni] * (inpv - cmv[ni]);   // pw*inp + comp
          const float dist = 1.f / (1.f + __expf(-zz));
          s1 += e;
          s2 += dist * e;
        }
#pragma unroll
        for (int off = 1; off < 16; off <<= 1) {
          s1 += __shfl_xor(s1, off);
          s2 += __shfl_xor(s2, off);
        }
        if (lr == 0) {
          s1p[row] = s1;
          s2p[row] = s2;
        }
      }
    }
  }
}

// ---------------- finalize: slice-reduce, tree product, leaf matmul, softmax ----------------
__global__ void k_finalize(const float* __restrict__ S1, const float* __restrict__ S2,
                           const float* __restrict__ leaf_out, float* __restrict__ out) {
  const int r    = (blockIdx.x * 256 + threadIdx.x) >> 6;  // one wave per row
  const int lane = threadIdx.x & 63;
  float pb[31];
  pb[0] = 1.f;
#pragma unroll
  for (int n = 0; n < 15; ++n) {
    float a1 = 0.f, a2 = 0.f;
#pragma unroll
    for (int s = 0; s < 16; ++s) {
      a1 += S1[((size_t)n * 16 + s) * NROWS + r];
      a2 += S2[((size_t)n * 16 + s) * NROWS + r];
    }
    const float p = a2 / a1;
    pb[2 * n + 1] = pb[n] * (1.f - p);
    pb[2 * n + 2] = pb[n] * p;
  }
  float a = 0.f;
#pragma unroll
  for (int i = 0; i < 16; ++i) a += pb[15 + i] * leaf_out[i * 64 + lane];
  float m = a;
#pragma unroll
  for (int off = 1; off < 64; off <<= 1) m = fmaxf(m, __shfl_xor(m, off));
  const float e = __expf(a - m);
  float s = e;
#pragma unroll
  for (int off = 1; off < 64; off <<= 1) s += __shfl_xor(s, off);
  out[(size_t)r * 64 + lane] = e / s;
}

// ---------------- workspace layout (bytes) ----------------
static constexpr size_t O_S1   = 0;                               // 15*16*8192 f32
static constexpr size_t O_S2   = O_S1 + (size_t)15 * 16 * NROWS * 4;
static constexpr size_t O_XSUM = O_S2 + (size_t)15 * 16 * NROWS * 4;
static constexpr size_t O_CS   = O_XSUM + 512 * 4;                // 7 x 512 f32
static constexpr size_t O_ZEND = O_CS + 7 * 512 * 4;              // end of zeroed scalars
static constexpr size_t O_XB   = O_ZEND;                          // bf16 x [8192,512]
static constexpr size_t O_OUTS = O_XB + (size_t)NROWS * HALFD * 2;
static constexpr size_t O_CW0  = O_OUTS + 7 * (size_t)NROWS * HALFD * 2;
static constexpr size_t O_AW0  = O_CW0 + (size_t)512 * 512 * 2;
static constexpr size_t O_CW   = O_AW0 + (size_t)512 * 512 * 2;
static constexpr size_t O_AW   = O_CW + (size_t)14 * 512 * 1024 * 2;

extern "C" void kernel_launch(void* const* d_in, const int* in_sizes, int n_in,
                              void* d_out, int out_size, void* d_ws, size_t ws_size,
                              hipStream_t stream) {
  const float* x        = (const float*)d_in[0];
  const float* calc_b0  = (const float*)d_in[2];
  const float* prob_w0  = (const float*)d_in[3];
  const float* attn_b0  = (const float*)d_in[5];
  const float* calc_b   = (const float*)d_in[7];
  const float* prob_w   = (const float*)d_in[8];
  const float* attn_b   = (const float*)d_in[10];
  const float* leaf_out = (const float*)d_in[11];
  float* out = (float*)d_out;
  char* ws = (char*)d_ws;

  float* S1   = (float*)(ws + O_S1);
  float* S2   = (float*)(ws + O_S2);
  float* xsum = (float*)(ws + O_XSUM);
  float* cs   = (float*)(ws + O_CS);  // cs + n*512 = colsum of outs[n]
  __hip_bfloat16* xb   = (__hip_bfloat16*)(ws + O_XB);
  __hip_bfloat16* outs = (__hip_bfloat16*)(ws + O_OUTS);
  __hip_bfloat16* cW0b = (__hip_bfloat16*)(ws + O_CW0);
  __hip_bfloat16* aW0b = (__hip_bfloat16*)(ws + O_AW0);
  __hip_bfloat16* cWb  = (__hip_bfloat16*)(ws + O_CW);
  __hip_bfloat16* aWb  = (__hip_bfloat16*)(ws + O_AW);
  const size_t OSZ = (size_t)NROWS * HALFD;  // elements per outs buffer
  const size_t NSL = (size_t)16 * NROWS;     // slice-block per node

  // Trimmed zero-init: node-0 slice blocks of S1/S2 (slices 8..15 unwritten at
  // gx=4) + xsum + cs. Nodes 1..14 slices are fully written by k_gemm.
  hipMemsetAsync(S1, 0, NSL * 4, stream);
  hipMemsetAsync(S2, 0, NSL * 4, stream);
  hipMemsetAsync(ws + O_XSUM, 0, O_ZEND - O_XSUM, stream);

  // merged converts (elements all divisible by 1024)
  {
    CvtArgs ca{};
    ca.src[0] = x;                     ca.dst[0] = xb;   ca.nblk[0] = NROWS * HALFD / 1024;
    ca.src[1] = (const float*)d_in[1]; ca.dst[1] = cW0b; ca.nblk[1] = 512 * 512 / 1024;
    ca.src[2] = (const float*)d_in[4]; ca.dst[2] = aW0b; ca.nblk[2] = 512 * 512 / 1024;
    ca.src[3] = (const float*)d_in[6]; ca.dst[3] = cWb;  ca.nblk[3] = 14 * 512 * 1024 / 1024;
    ca.src[4] = (const float*)d_in[9]; ca.dst[4] = aWb;  ca.nblk[4] = 14 * 1024 * 1024 / 1024;
    int tot = ca.nblk[0] + ca.nblk[1] + ca.nblk[2] + ca.nblk[3] + ca.nblk[4];
    k_cvt<<<tot, 256, 0, stream>>>(ca);
  }
  k_colsum_f32<<<dim3(2, 32), 256, 0, stream>>>(x, xsum);

  // ---- stage 0: root calc + root attn (K=512, N=512) ----
  {
    GArgs ga{};
    ga.mode[0] = 0; ga.gx[0] = 4; ga.K[0] = 512;
    ga.A0[0] = xb; ga.Bw[0] = cW0b; ga.bias[0] = calc_b0;
    ga.outB[0] = outs; ga.csOut[0] = cs;
    ga.mode[1] = 1; ga.gx[1] = 4; ga.K[1] = 512;
    ga.A0[1] = xb; ga.Bw[1] = aW0b; ga.bias[1] = attn_b0;
    ga.pw[1] = prob_w0; ga.cm0[1] = xsum;
    ga.S1[1] = S1; ga.S2[1] = S2;
    k_gemm<<<dim3(4, 64, 2), 256, 0, stream>>>(ga, xb, xsum);
  }
  // ---- stage 1: calc nodes 1,2 + attn nodes 1,2 (A=[outs0|x]) ----
  {
    GArgs ga{};
    ga.mode[0] = 0; ga.gx[0] = 8; ga.K[0] = 1024;
    ga.A0[0] = outs; ga.Bw[0] = cWb; ga.bias[0] = calc_b;
    ga.outB[0] = outs + OSZ; ga.csOut[0] = cs + 512;
    ga.mode[1] = 1; ga.gx[1] = 16; ga.K[1] = 1024;
    ga.A0[1] = outs; ga.Bw[1] = aWb; ga.bias[1] = attn_b;
    ga.pw[1] = prob_w; ga.cm0[1] = cs;
    ga.S1[1] = S1 + (size_t)1 * NSL; ga.S2[1] = S2 + (size_t)1 * NSL;
    k_gemm<<<dim3(16, 64, 2), 256, 0, stream>>>(ga, xb, xsum);
  }
  // ---- stage 2: calc nodes 3,4 (outs1) & 5,6 (outs2) + attn nodes 3..6 ----
  {
    GArgs ga{};
    for (int i = 0; i < 2; ++i) {
      ga.mode[i] = 0; ga.gx[i] = 8; ga.K[i] = 1024;
      ga.A0[i] = outs + (size_t)(1 + i) * OSZ;
      ga.Bw[i] = cWb + (size_t)(2 + 2 * i) * 512 * 1024;
      ga.bias[i] = calc_b + (2 + 2 * i) * 512;
      ga.outB[i] = outs + (size_t)(3 + 2 * i) * OSZ;
      ga.csOut[i] = cs + (size_t)(3 + 2 * i) * 512;
    }
    for (int i = 0; i < 2; ++i) {
      const int zi = 2 + i;
      ga.mode[zi] = 1; ga.gx[zi] = 16; ga.K[zi] = 1024;
      ga.A0[zi] = outs + (size_t)(1 + i) * OSZ;
      ga.Bw[zi] = aWb + (size_t)(2 + 2 * i) * 1024 * 1024;
      ga.bias[zi] = attn_b + (2 + 2 * i) * 1024;
      ga.pw[zi] = prob_w + (2 + 2 * i) * 1024;
      ga.cm0[zi] = cs + (size_t)(1 + i) * 512;
      ga.S1[zi] = S1 + (size_t)(3 + 2 * i) * NSL;
      ga.S2[zi] = S2 + (size_t)(3 + 2 * i) * NSL;
    }
    k_gemm<<<dim3(16, 64, 4), 256, 0, stream>>>(ga, xb, xsum);
  }
  // ---- stage 3: attn nodes 7..14 (outs[7..14] dead) ----
  {
    GArgs ga{};
    for (int i = 0; i < 4; ++i) {
      ga.mode[i] = 1; ga.gx[i] = 16; ga.K[i] = 1024;
      ga.A0[i] = outs + (size_t)(3 + i) * OSZ;
      ga.Bw[i] = aWb + (size_t)(6 + 2 * i) * 1024 * 1024;
      ga.bias[i] = attn_b + (6 + 2 * i) * 1024;
      ga.pw[i] = prob_w + (6 + 2 * i) * 1024;
      ga.cm0[i] = cs + (size_t)(3 + i) * 512;
      ga.S1[i] = S1 + (size_t)(7 + 2 * i) * NSL;
      ga.S2[i] = S2 + (size_t)(7 + 2 * i) * NSL;
    }
    k_gemm<<<dim3(16, 64, 4), 256, 0, stream>>>(ga, xb, xsum);
  }

  // ---- finalize ----
  k_finalize<<<NROWS * 64 / 256, 256, 0, stream>>>(S1, S2, leaf_out, out);
}